// Round 4
// baseline (43.631 us; speedup 1.0000x reference)
//
#include <hip/hip_runtime.h>
#include <stdint.h>

typedef _Float16 f16;
typedef f16   f16x2 __attribute__((ext_vector_type(2)));
typedef f16   f16x8 __attribute__((ext_vector_type(8)));
typedef float f32x4 __attribute__((ext_vector_type(4)));

static constexpr int M_ = 64;
static constexpr int K_ = 4096;
static constexpr int N_ = 14336;

// ---------------- x fp32 -> fp16 (row-major [64][4096]) ----------------
__global__ void xconv_kernel(const float* __restrict__ x, uint4* __restrict__ xh) {
    int t = blockIdx.x * blockDim.x + threadIdx.x;      // 32768 threads, 8 elems each
    const float4* p = reinterpret_cast<const float4*>(x) + 2 * t;
    float4 a = p[0], b = p[1];
    union { f16x8 h; uint4 v; } z;
    z.h[0] = (f16)a.x; z.h[1] = (f16)a.y; z.h[2] = (f16)a.z; z.h[3] = (f16)a.w;
    z.h[4] = (f16)b.x; z.h[5] = (f16)b.y; z.h[6] = (f16)b.z; z.h[7] = (f16)b.w;
    xh[t] = z.v;
}

// ---------------- fused dequant + GEMM, register-only main loop ----------------
// grid = 224 (BN=64), block = 512 = 8 waves. Wave w owns K-chunk [w*512,(w+1)*512)
// and computes the FULL 64x64 block tile for that chunk (4 mt x 4 nt, acc=64 VGPR).
// No LDS / no barriers in the main loop; A and B stream global->reg with
// compile-time immediate offsets. K-partials tree-reduced via LDS at the end.
//
// Dequant: nibble n -> f16 via 0x6400|n = 1024+n (exact), pk_add(-1032) -> n-8
// (exact), pk_mul(s) -> (n-8)*s with a single rounding.
// Packed dword nibble p -> frag slot 2p (k=+2p), nibble p+4 -> slot 2p+1.
template<bool PRE>
__global__ __launch_bounds__(512)
void gemm_kernel(const float* __restrict__ xf, const f16x8* __restrict__ xh8,
                 const uint* __restrict__ bpk, const float* __restrict__ s,
                 float* __restrict__ out)
{
    __shared__ f32x4 red[4][1024];                      // 64 KB, epilogue only
    const int lane = threadIdx.x & 63;
    const int w    = threadIdx.x >> 6;                  // k-chunk id 0..7
    const int h    = lane >> 4;                         // 0..3
    const int l16  = lane & 15;
    const int n0   = blockIdx.x * 64;

    // per-group packed f16 scales for this lane's 4 n-subtiles
    f16x2 spk[4][4];
    #pragma unroll
    for (int g = 0; g < 4; ++g)
        #pragma unroll
        for (int nt = 0; nt < 4; ++nt) {
            float sv = s[(size_t)(w * 4 + g) * N_ + (n0 + nt * 16 + l16)];
            f16 sh = (f16)sv;
            f16x2 t2 = {sh, sh};
            spk[g][nt] = t2;
        }

    // base element indices: dword/f16x8 index = row*512 + w*64 + g*16 + t*4 + h
    size_t cb[4], ca[4];
    #pragma unroll
    for (int nt = 0; nt < 4; ++nt)
        cb[nt] = (size_t)(n0 + nt * 16 + l16) * 512 + w * 64 + h;
    #pragma unroll
    for (int mt = 0; mt < 4; ++mt)
        ca[mt] = (size_t)(mt * 16 + l16) * 512 + w * 64 + h;

    f32x4 acc[4][4];
    #pragma unroll
    for (int nt = 0; nt < 4; ++nt)
        #pragma unroll
        for (int mt = 0; mt < 4; ++mt)
            acc[nt][mt] = f32x4{0.f, 0.f, 0.f, 0.f};

    // raw B double-buffer in regs; prologue loads group 0
    uint br[2][16];
    #pragma unroll
    for (int nt = 0; nt < 4; ++nt)
        #pragma unroll
        for (int t = 0; t < 4; ++t)
            br[0][nt * 4 + t] = bpk[cb[nt] + t * 4];

    const f16 m1032 = (f16)(-1032.0f);
    const f16x2 mc = {m1032, m1032};

    #pragma unroll
    for (int g = 0; g < 4; ++g) {                       // 4 scale-groups of 128 k
        // batch-load all 16 A fragments of this group (deep ILP, imm offsets)
        f16x8 a[4][4];
        #pragma unroll
        for (int t = 0; t < 4; ++t)
            #pragma unroll
            for (int mt = 0; mt < 4; ++mt) {
                if constexpr (PRE) {
                    a[t][mt] = xh8[ca[mt] + g * 16 + t * 4];
                } else {
                    const float* xp = xf + (size_t)(mt * 16 + l16) * K_ + w * 512 + g * 128 + t * 32 + h * 8;
                    float4 f0 = *reinterpret_cast<const float4*>(xp);
                    float4 f1 = *reinterpret_cast<const float4*>(xp + 4);
                    f16x8 av;
                    av[0] = (f16)f0.x; av[1] = (f16)f0.y; av[2] = (f16)f0.z; av[3] = (f16)f0.w;
                    av[4] = (f16)f1.x; av[5] = (f16)f1.y; av[6] = (f16)f1.z; av[7] = (f16)f1.w;
                    a[t][mt] = av;
                }
            }
        // prefetch next group's raw B
        if (g < 3) {
            #pragma unroll
            for (int nt = 0; nt < 4; ++nt)
                #pragma unroll
                for (int t = 0; t < 4; ++t)
                    br[(g + 1) & 1][nt * 4 + t] = bpk[cb[nt] + (g + 1) * 16 + t * 4];
        }
        #pragma unroll
        for (int t = 0; t < 4; ++t) {                   // k-steps of 32
            f16x8 bq[4];
            #pragma unroll
            for (int nt = 0; nt < 4; ++nt) {
                const uint u = br[g & 1][nt * 4 + t];
                union { f16x2 h2; uint uu; } um;
                union { f16x2 h2[4]; f16x8 v; } ob;
                #pragma unroll
                for (int p = 0; p < 4; ++p) {
                    um.uu = 0x64006400u | ((u >> (4 * p)) & 0x000F000Fu);
                    f16x2 v2 = um.h2 + mc;              // exact: (1024+n)-1032 = n-8
                    ob.h2[p] = v2 * spk[g][nt];         // one rounding
                }
                bq[nt] = ob.v;
            }
            #pragma unroll
            for (int nt = 0; nt < 4; ++nt)
                #pragma unroll
                for (int mt = 0; mt < 4; ++mt)
                    acc[nt][mt] = __builtin_amdgcn_mfma_f32_16x16x32_f16(a[t][mt], bq[nt], acc[nt][mt], 0, 0, 0);
        }
    }

    // ---- binary-tree reduction of the 8 K-partials through LDS ----
    if (w >= 4) {
        #pragma unroll
        for (int nt = 0; nt < 4; ++nt)
            #pragma unroll
            for (int mt = 0; mt < 4; ++mt)
                red[w - 4][(nt * 4 + mt) * 64 + lane] = acc[nt][mt];
    }
    __syncthreads();
    if (w < 4) {
        #pragma unroll
        for (int nt = 0; nt < 4; ++nt)
            #pragma unroll
            for (int mt = 0; mt < 4; ++mt)
                acc[nt][mt] += red[w][(nt * 4 + mt) * 64 + lane];
    }
    __syncthreads();
    if (w == 2 || w == 3) {
        #pragma unroll
        for (int nt = 0; nt < 4; ++nt)
            #pragma unroll
            for (int mt = 0; mt < 4; ++mt)
                red[w - 2][(nt * 4 + mt) * 64 + lane] = acc[nt][mt];
    }
    __syncthreads();
    if (w < 2) {
        #pragma unroll
        for (int nt = 0; nt < 4; ++nt)
            #pragma unroll
            for (int mt = 0; mt < 4; ++mt)
                acc[nt][mt] += red[w][(nt * 4 + mt) * 64 + lane];
    }
    __syncthreads();
    if (w == 1) {
        #pragma unroll
        for (int nt = 0; nt < 4; ++nt)
            #pragma unroll
            for (int mt = 0; mt < 4; ++mt)
                red[0][(nt * 4 + mt) * 64 + lane] = acc[nt][mt];
    }
    __syncthreads();
    if (w == 0) {
        #pragma unroll
        for (int nt = 0; nt < 4; ++nt)
            #pragma unroll
            for (int mt = 0; mt < 4; ++mt) {
                acc[nt][mt] += red[0][(nt * 4 + mt) * 64 + lane];
                // C/D layout: row = mt*16 + h*4 + q, col = n0 + nt*16 + l16
                #pragma unroll
                for (int q = 0; q < 4; ++q)
                    out[(size_t)(mt * 16 + h * 4 + q) * N_ + (n0 + nt * 16 + l16)] = acc[nt][mt][q];
            }
    }
}

extern "C" void kernel_launch(void* const* d_in, const int* in_sizes, int n_in,
                              void* d_out, int out_size, void* d_ws, size_t ws_size,
                              hipStream_t stream) {
    const float* x   = (const float*)d_in[0];
    const uint*  bpk = (const uint*)d_in[1];
    const float* s   = (const float*)d_in[2];
    float*       out = (float*)d_out;

    if (ws_size >= (size_t)(M_ * K_ * 2)) {
        xconv_kernel<<<128, 256, 0, stream>>>(x, (uint4*)d_ws);
        gemm_kernel<true><<<224, 512, 0, stream>>>(x, (const f16x8*)d_ws, bpk, s, out);
    } else {
        gemm_kernel<false><<<224, 512, 0, stream>>>(x, nullptr, bpk, s, out);
    }
}

// Round 5
// 24.843 us; speedup vs baseline: 1.7563x; 1.7563x over previous
//
#include <hip/hip_runtime.h>
#include <stdint.h>

typedef _Float16 f16;
typedef f16   f16x2 __attribute__((ext_vector_type(2)));
typedef f16   f16x8 __attribute__((ext_vector_type(8)));
typedef float f32x4 __attribute__((ext_vector_type(4)));

static constexpr int M_ = 64;
static constexpr int K_ = 4096;
static constexpr int N_ = 14336;

// x fp32 [64][4096] -> f16, tiled into MFMA-fragment order:
// f16x8-slot ((kg*4+mt)*64 + h*16 + l16) holds x[mt*16+l16][(kg*4+h)*8 .. +8)
// so a wave's A-fragment load is base + lane*16B (fully coalesced).
__global__ void xconv_kernel(const float* __restrict__ x, uint4* __restrict__ xt) {
    int t = blockIdx.x * blockDim.x + threadIdx.x;      // 32768 threads
    int row = t >> 9, kb = t & 511;
    int kg = kb >> 2, h = kb & 3, mt = row >> 4, l16 = row & 15;
    int dst = (kg * 4 + mt) * 64 + h * 16 + l16;
    const float4* p = reinterpret_cast<const float4*>(x) + 2 * (size_t)t;   // coalesced read
    float4 a = p[0], b = p[1];
    union { f16x8 h8; uint4 v; } z;
    z.h8[0] = (f16)a.x; z.h8[1] = (f16)a.y; z.h8[2] = (f16)a.z; z.h8[3] = (f16)a.w;
    z.h8[4] = (f16)b.x; z.h8[5] = (f16)b.y; z.h8[6] = (f16)b.z; z.h8[7] = (f16)b.w;
    xt[dst] = z.v;                                      // scattered 16B write (cheap)
}

__device__ __forceinline__ void gload_lds16(const void* g, void* l) {
    __builtin_amdgcn_global_load_lds(
        (const __attribute__((address_space(1))) void*)g,
        (__attribute__((address_space(3))) void*)l, 16, 0, 0);
}

// nibble->f16 dequant: 0x6400|n = 1024+n exact; pk_add(-1032) -> n-8 exact; pk_mul(s).
// packed dword nibble p -> frag slot 2p, nibble p+4 -> slot 2p+1 (folds pack-perm).
__device__ __forceinline__ f16x8 dequant(uint u, f16x2 sc) {
    const f16 m = (f16)(-1032.0f);
    const f16x2 mc = {m, m};
    union { f16x2 h2; uint uu; } um;
    union { f16x2 h2[4]; f16x8 v; } ob;
    #pragma unroll
    for (int p = 0; p < 4; ++p) {
        um.uu = 0x64006400u | ((u >> (4 * p)) & 0x000F000Fu);
        ob.h2[p] = (um.h2 + mc) * sc;
    }
    return ob.v;
}

// grid=448 (BN=32), block=512=8 waves. Wave w owns K-chunk [w*512,(w+1)*512) =
// 4 scale-groups; computes 4mt x 2nt. B staged per-wave-private in LDS
// (2x2KB double buffer, zero barriers in main loop, counted vmcnt).
// 8 K-partials tree-reduced via LDS at the end; all waves store.
template<bool PRE>
__global__ __launch_bounds__(512, 4)
void gemm_kernel(const float* __restrict__ xf, const f16x8* __restrict__ xt,
                 const uint* __restrict__ bpk, const float* __restrict__ s,
                 float* __restrict__ out)
{
    __shared__ __align__(16) uint lbs[8192];            // 32 KB
    const int lane = threadIdx.x & 63;
    const int w    = threadIdx.x >> 6;                  // K-chunk id 0..7
    const int h    = lane >> 4;
    const int l16  = lane & 15;
    const int n0   = blockIdx.x * 32;

    // per-group packed f16 scales (coalesced 64B/16-lane reads)
    f16x2 spk[4][2];
    #pragma unroll
    for (int g = 0; g < 4; ++g)
        #pragma unroll
        for (int nt = 0; nt < 2; ++nt) {
            float sv = s[(size_t)(w * 4 + g) * N_ + n0 + nt * 16 + l16];
            f16 sh = (f16)sv;
            spk[g][nt] = f16x2{sh, sh};
        }

    // stage wave-private B slice for local group gl into buf gl&1.
    // LDS dword (w*1024 + buf*512 + j*256 + lane*4 + d) <- bpk[n0+j*16+l16][w*64+gl*16+h*4+d]
    auto stage = [&](int gl) {
        const int buf = gl & 1;
        const int gdw = w * 64 + gl * 16 + h * 4;
        gload_lds16(bpk + (size_t)(n0 +      l16) * 512 + gdw, &lbs[w * 1024 + buf * 512]);
        gload_lds16(bpk + (size_t)(n0 + 16 + l16) * 512 + gdw, &lbs[w * 1024 + buf * 512 + 256]);
    };

    const f16x8* aw = xt + (size_t)w * 4096 + lane;     // fragment-tiled A base
    auto loadA = [&](int g, int t, int mt) -> f16x8 {
        if constexpr (PRE) {
            return aw[((g * 4 + t) * 4 + mt) * 64];
        } else {
            const float* xp = xf + (size_t)(mt * 16 + l16) * K_ + (size_t)(w * 64 + g * 16 + t * 4 + h) * 8;
            float4 f0 = *reinterpret_cast<const float4*>(xp);
            float4 f1 = *reinterpret_cast<const float4*>(xp + 4);
            f16x8 av;
            av[0] = (f16)f0.x; av[1] = (f16)f0.y; av[2] = (f16)f0.z; av[3] = (f16)f0.w;
            av[4] = (f16)f1.x; av[5] = (f16)f1.y; av[6] = (f16)f1.z; av[7] = (f16)f1.w;
            return av;
        }
    };

    stage(0);

    f32x4 acc[2][4];
    #pragma unroll
    for (int nt = 0; nt < 2; ++nt)
        #pragma unroll
        for (int mt = 0; mt < 4; ++mt) acc[nt][mt] = f32x4{0.f, 0.f, 0.f, 0.f};

    #pragma unroll
    for (int g = 0; g < 4; ++g) {
        if (g < 3) stage(g + 1);                        // double-buffer prefetch
        f16x8 a[2][4];
        #pragma unroll
        for (int mt = 0; mt < 4; ++mt) a[0][mt] = loadA(g, 0, mt);
        // ensure stage(g) (the 2 oldest outstanding vmem ops) has landed;
        // leaves stage(g+1) + A-loads in flight.
        if constexpr (PRE) {
            if (g < 3) { asm volatile("s_waitcnt vmcnt(6)" ::: "memory"); }
            else       { asm volatile("s_waitcnt vmcnt(4)" ::: "memory"); }
        } else {
            asm volatile("s_waitcnt vmcnt(0)" ::: "memory");
        }
        __builtin_amdgcn_sched_barrier(0);
        const int bbase = w * 1024 + (g & 1) * 512 + l16 * 4 + h;
        #pragma unroll
        for (int t = 0; t < 4; ++t) {
            if (t < 3) {
                #pragma unroll
                for (int mt = 0; mt < 4; ++mt) a[(t + 1) & 1][mt] = loadA(g, t + 1, mt);
            }
            const uint u0 = lbs[bbase + t * 64];        // nt=0 (contig wave read, no conflict)
            const uint u1 = lbs[bbase + t * 64 + 256];  // nt=1
            const f16x8 b0 = dequant(u0, spk[g][0]);
            const f16x8 b1 = dequant(u1, spk[g][1]);
            #pragma unroll
            for (int mt = 0; mt < 4; ++mt)
                acc[0][mt] = __builtin_amdgcn_mfma_f32_16x16x32_f16(a[t & 1][mt], b0, acc[0][mt], 0, 0, 0);
            #pragma unroll
            for (int mt = 0; mt < 4; ++mt)
                acc[1][mt] = __builtin_amdgcn_mfma_f32_16x16x32_f16(a[t & 1][mt], b1, acc[1][mt], 0, 0, 0);
        }
    }

    // ---- tree-reduce 8 K-partials via LDS (alias B region, 32 KB) ----
    f32x4* red = reinterpret_cast<f32x4*>(lbs);
    __syncthreads();
    if (w >= 4) {
        #pragma unroll
        for (int nt = 0; nt < 2; ++nt)
            #pragma unroll
            for (int mt = 0; mt < 4; ++mt)
                red[((w - 4) * 8 + nt * 4 + mt) * 64 + lane] = acc[nt][mt];
    }
    __syncthreads();
    if (w < 4) {
        #pragma unroll
        for (int nt = 0; nt < 2; ++nt)
            #pragma unroll
            for (int mt = 0; mt < 4; ++mt)
                acc[nt][mt] += red[(w * 8 + nt * 4 + mt) * 64 + lane];
    }
    __syncthreads();
    if (w == 2 || w == 3) {
        #pragma unroll
        for (int nt = 0; nt < 2; ++nt)
            #pragma unroll
            for (int mt = 0; mt < 4; ++mt)
                red[((w - 2) * 8 + nt * 4 + mt) * 64 + lane] = acc[nt][mt];
    }
    __syncthreads();
    if (w < 2) {
        #pragma unroll
        for (int nt = 0; nt < 2; ++nt)
            #pragma unroll
            for (int mt = 0; mt < 4; ++mt)
                acc[nt][mt] += red[(w * 8 + nt * 4 + mt) * 64 + lane];
    }
    __syncthreads();
    if (w < 2) {
        #pragma unroll
        for (int nt = 0; nt < 2; ++nt)
            #pragma unroll
            for (int mt = 0; mt < 4; ++mt)
                red[(w * 8 + nt * 4 + mt) * 64 + lane] = acc[nt][mt];
    }
    __syncthreads();
    {   // every wave stores one (nt,mt) slot: final = w0-half + w1-half
        const int slot = w;
        f32x4 v = red[slot * 64 + lane];
        v += red[(8 + slot) * 64 + lane];
        const int nt = slot >> 2, mt = slot & 3;
        #pragma unroll
        for (int q = 0; q < 4; ++q)
            out[(size_t)(mt * 16 + h * 4 + q) * N_ + (n0 + nt * 16 + l16)] = v[q];
    }
}

extern "C" void kernel_launch(void* const* d_in, const int* in_sizes, int n_in,
                              void* d_out, int out_size, void* d_ws, size_t ws_size,
                              hipStream_t stream) {
    const float* x   = (const float*)d_in[0];
    const uint*  bpk = (const uint*)d_in[1];
    const float* s   = (const float*)d_in[2];
    float*       out = (float*)d_out;

    if (ws_size >= (size_t)(M_ * K_ * 2)) {
        xconv_kernel<<<128, 256, 0, stream>>>(x, (uint4*)d_ws);
        gemm_kernel<true><<<448, 512, 0, stream>>>(x, (const f16x8*)d_ws, bpk, s, out);
    } else {
        gemm_kernel<false><<<448, 512, 0, stream>>>(x, nullptr, bpk, s, out);
    }
}